// Round 1
// baseline (167.801 us; speedup 1.0000x reference)
//
#include <hip/hip_runtime.h>
#include <math.h>

#define HW (224 * 224)          // 50176 pixels
#define NSAMP 1024
#define NCHUNK 8
#define CHUNK (NSAMP / NCHUNK)  // 128 samples per chunk
#define EPSW 1e-10f

// -------- Kernel 1: per-pixel partial sums over a chunk of samples --------
// part layout (floats): [0]=Wa  [1]=Sa  [2]=Wb  [3]=St  [4]=Sc  [5]=Ss, each HW wide
__global__ __launch_bounds__(256) void relax_partial(
    const float* __restrict__ A, const float* __restrict__ B,
    const float* __restrict__ sa, const float* __restrict__ st,
    const float* __restrict__ sc, const float* __restrict__ ss,
    float* __restrict__ part) {
  __shared__ float4 s4[CHUNK];
  const int tid = threadIdx.x;
  const int i0 = blockIdx.y * CHUNK;
  if (tid < CHUNK)
    s4[tid] = make_float4(sa[i0 + tid], st[i0 + tid], sc[i0 + tid], ss[i0 + tid]);
  __syncthreads();

  const int p = blockIdx.x * 256 + tid;
  const float* ap = A + (size_t)i0 * HW + p;
  const float* bp = B + (size_t)i0 * HW + p;

  float Wa = 0.f, Sa = 0.f, Wb = 0.f, St = 0.f, Sc = 0.f, Ss = 0.f;
#pragma unroll 8
  for (int j = 0; j < CHUNK; ++j) {
    const float ma = ap[(size_t)j * HW];
    const float mb = bp[(size_t)j * HW];
    const float4 sv = s4[j];
    Wa += ma;
    Sa = fmaf(ma, sv.x, Sa);
    Wb += mb;
    St = fmaf(mb, sv.y, St);
    Sc = fmaf(mb, sv.z, Sc);
    Ss = fmaf(mb, sv.w, Ss);
  }
  atomicAdd(&part[0 * HW + p], Wa);
  atomicAdd(&part[1 * HW + p], Sa);
  atomicAdd(&part[2 * HW + p], Wb);
  atomicAdd(&part[3 * HW + p], St);
  atomicAdd(&part[4 * HW + p], Sc);
  atomicAdd(&part[5 * HW + p], Ss);
}

// -------- Kernel 2: Σx and Σx² per map (double, wave-shuffle reduce) --------
// stats layout (doubles): [2m] = Σx_m, [2m+1] = Σx_m², m = 0..3
__global__ __launch_bounds__(256) void relax_stats(
    const float* __restrict__ part, double* __restrict__ stats) {
  const int p = blockIdx.x * 256 + threadIdx.x;
  const float Wa = part[0 * HW + p], Sa = part[1 * HW + p];
  const float Wb = part[2 * HW + p];
  const float St = part[3 * HW + p], Sc = part[4 * HW + p], Ss = part[5 * HW + p];

  const float x0 = Sa / (EPSW + Wa);
  const float invb = 1.0f / (EPSW + Wb);
  const float x1 = St * invb, x2 = Sc * invb, x3 = Ss * invb;

  double v[8];
  v[0] = x0; v[1] = (double)x0 * x0;
  v[2] = x1; v[3] = (double)x1 * x1;
  v[4] = x2; v[5] = (double)x2 * x2;
  v[6] = x3; v[7] = (double)x3 * x3;

#pragma unroll
  for (int k = 0; k < 8; ++k)
#pragma unroll
    for (int off = 32; off; off >>= 1)
      v[k] += __shfl_down(v[k], off);

  if ((threadIdx.x & 63) == 0) {
#pragma unroll
    for (int k = 0; k < 8; ++k) atomicAdd(&stats[k], v[k]);
  }
}

// -------- Kernel 3: normalize and write [4, H, W] --------
__global__ __launch_bounds__(256) void relax_norm(
    const float* __restrict__ part, const double* __restrict__ stats,
    float* __restrict__ out) {
  const int p = blockIdx.x * 256 + threadIdx.x;
  const int m = blockIdx.y;

  float x;
  if (m == 0) {
    x = part[1 * HW + p] / (EPSW + part[0 * HW + p]);
  } else {
    x = part[(2 + m) * HW + p] / (EPSW + part[2 * HW + p]);
  }
  const double sum = stats[2 * m], sumsq = stats[2 * m + 1];
  const double mean = sum / (double)HW;
  const double var = (sumsq - sum * sum / (double)HW) / (double)(HW - 1);
  const float istd = (float)(1.0 / sqrt(var));
  out[m * HW + p] = (x - (float)mean) * istd;
}

extern "C" void kernel_launch(void* const* d_in, const int* in_sizes, int n_in,
                              void* d_out, int out_size, void* d_ws, size_t ws_size,
                              hipStream_t stream) {
  const float* A  = (const float*)d_in[0];  // masks_a  [N,H,W]
  const float* sa = (const float*)d_in[1];  // sims     [N]
  const float* B  = (const float*)d_in[2];  // masks_b  [N,H,W]
  const float* st = (const float*)d_in[3];  // sims_texture [N]
  const float* sc = (const float*)d_in[4];  // sims_color   [N]
  const float* ss = (const float*)d_in[5];  // sims_shape   [N]
  float* out = (float*)d_out;               // [4,H,W] fp32

  // workspace: [0,64)  : 8 doubles (stats)
  //            [64, 64+6*HW*4) : partial sums
  double* stats = (double*)d_ws;
  float* part = (float*)((char*)d_ws + 64);

  hipMemsetAsync(d_ws, 0, 64 + (size_t)6 * HW * sizeof(float), stream);

  dim3 g1(HW / 256, NCHUNK);
  relax_partial<<<g1, 256, 0, stream>>>(A, B, sa, st, sc, ss, part);
  relax_stats<<<dim3(HW / 256), 256, 0, stream>>>(part, stats);
  relax_norm<<<dim3(HW / 256, 4), 256, 0, stream>>>(part, stats, out);
}

// Round 2
// 164.727 us; speedup vs baseline: 1.0187x; 1.0187x over previous
//
#include <hip/hip_runtime.h>
#include <math.h>

#define HW (224 * 224)          // 50176 pixels
#define HW4 (HW / 4)            // 12544 float4 pixel-groups
#define NSAMP 1024
#define NCHUNK 16
#define CHUNK (NSAMP / NCHUNK)  // 64 samples per chunk
#define EPSW 1e-10f

__device__ __forceinline__ void fma4(float4& acc, const float4 m, const float s) {
  acc.x = fmaf(m.x, s, acc.x);
  acc.y = fmaf(m.y, s, acc.y);
  acc.z = fmaf(m.z, s, acc.z);
  acc.w = fmaf(m.w, s, acc.w);
}
__device__ __forceinline__ void add4(float4& acc, const float4 m) {
  acc.x += m.x; acc.y += m.y; acc.z += m.z; acc.w += m.w;
}

// -------- Kernel 1: per-pixel partial sums over a chunk of samples --------
// part layout (floats): [0]=Wa [1]=Sa [2]=Wb [3]=St [4]=Sc [5]=Ss, each HW wide
__global__ __launch_bounds__(256) void relax_partial(
    const float4* __restrict__ A4, const float4* __restrict__ B4,
    const float* __restrict__ sa, const float* __restrict__ st,
    const float* __restrict__ sc, const float* __restrict__ ss,
    float* __restrict__ part) {
  __shared__ float4 s4[CHUNK];
  const int tid = threadIdx.x;
  const int i0 = blockIdx.y * CHUNK;
  if (tid < CHUNK)
    s4[tid] = make_float4(sa[i0 + tid], st[i0 + tid], sc[i0 + tid], ss[i0 + tid]);
  __syncthreads();

  const int q = blockIdx.x * 256 + tid;            // float4-pixel index
  const float4* ap = A4 + (size_t)i0 * HW4 + q;
  const float4* bp = B4 + (size_t)i0 * HW4 + q;

  float4 Wa = {0,0,0,0}, Sa = {0,0,0,0}, Wb = {0,0,0,0};
  float4 St = {0,0,0,0}, Sc = {0,0,0,0}, Ss = {0,0,0,0};
#pragma unroll 4
  for (int j = 0; j < CHUNK; ++j) {
    const float4 ma = ap[(size_t)j * HW4];
    const float4 mb = bp[(size_t)j * HW4];
    const float4 sv = s4[j];
    add4(Wa, ma);
    fma4(Sa, ma, sv.x);
    add4(Wb, mb);
    fma4(St, mb, sv.y);
    fma4(Sc, mb, sv.z);
    fma4(Ss, mb, sv.w);
  }
  const int p = 4 * q;
  float* w;
  w = &part[0 * HW + p];
  atomicAdd(w + 0, Wa.x); atomicAdd(w + 1, Wa.y); atomicAdd(w + 2, Wa.z); atomicAdd(w + 3, Wa.w);
  w = &part[1 * HW + p];
  atomicAdd(w + 0, Sa.x); atomicAdd(w + 1, Sa.y); atomicAdd(w + 2, Sa.z); atomicAdd(w + 3, Sa.w);
  w = &part[2 * HW + p];
  atomicAdd(w + 0, Wb.x); atomicAdd(w + 1, Wb.y); atomicAdd(w + 2, Wb.z); atomicAdd(w + 3, Wb.w);
  w = &part[3 * HW + p];
  atomicAdd(w + 0, St.x); atomicAdd(w + 1, St.y); atomicAdd(w + 2, St.z); atomicAdd(w + 3, St.w);
  w = &part[4 * HW + p];
  atomicAdd(w + 0, Sc.x); atomicAdd(w + 1, Sc.y); atomicAdd(w + 2, Sc.z); atomicAdd(w + 3, Sc.w);
  w = &part[5 * HW + p];
  atomicAdd(w + 0, Ss.x); atomicAdd(w + 1, Ss.y); atomicAdd(w + 2, Ss.z); atomicAdd(w + 3, Ss.w);
}

// -------- Kernel 2: Σx and Σx² per map (double, wave-shuffle reduce) --------
// stats layout (doubles): [2m] = Σx_m, [2m+1] = Σx_m², m = 0..3
__global__ __launch_bounds__(256) void relax_stats(
    const float4* __restrict__ part4, double* __restrict__ stats) {
  const int q = blockIdx.x * 256 + threadIdx.x;   // [0, HW4)
  const float4 Wa = part4[0 * HW4 + q], Sa = part4[1 * HW4 + q];
  const float4 Wb = part4[2 * HW4 + q];
  const float4 St = part4[3 * HW4 + q], Sc = part4[4 * HW4 + q], Ss = part4[5 * HW4 + q];

  double v[8] = {0, 0, 0, 0, 0, 0, 0, 0};
  const float* wa = &Wa.x; const float* sa = &Sa.x; const float* wb = &Wb.x;
  const float* st = &St.x; const float* sc = &Sc.x; const float* ss = &Ss.x;
#pragma unroll
  for (int k = 0; k < 4; ++k) {
    const float x0 = sa[k] / (EPSW + wa[k]);
    const float invb = 1.0f / (EPSW + wb[k]);
    const float x1 = st[k] * invb, x2 = sc[k] * invb, x3 = ss[k] * invb;
    v[0] += x0; v[1] += (double)x0 * x0;
    v[2] += x1; v[3] += (double)x1 * x1;
    v[4] += x2; v[5] += (double)x2 * x2;
    v[6] += x3; v[7] += (double)x3 * x3;
  }

#pragma unroll
  for (int k = 0; k < 8; ++k)
#pragma unroll
    for (int off = 32; off; off >>= 1)
      v[k] += __shfl_down(v[k], off);

  if ((threadIdx.x & 63) == 0) {
#pragma unroll
    for (int k = 0; k < 8; ++k) atomicAdd(&stats[k], v[k]);
  }
}

// -------- Kernel 3: normalize and write [4, H, W] --------
__global__ __launch_bounds__(256) void relax_norm(
    const float4* __restrict__ part4, const double* __restrict__ stats,
    float4* __restrict__ out4) {
  const int q = blockIdx.x * 256 + threadIdx.x;
  const int m = blockIdx.y;

  float4 x;
  if (m == 0) {
    const float4 W = part4[0 * HW4 + q], S = part4[1 * HW4 + q];
    x = make_float4(S.x / (EPSW + W.x), S.y / (EPSW + W.y),
                    S.z / (EPSW + W.z), S.w / (EPSW + W.w));
  } else {
    const float4 W = part4[2 * HW4 + q], S = part4[(2 + m) * HW4 + q];
    x = make_float4(S.x / (EPSW + W.x), S.y / (EPSW + W.y),
                    S.z / (EPSW + W.z), S.w / (EPSW + W.w));
  }
  const double sum = stats[2 * m], sumsq = stats[2 * m + 1];
  const double mean = sum / (double)HW;
  const double var = (sumsq - sum * sum / (double)HW) / (double)(HW - 1);
  const float istd = (float)(1.0 / sqrt(var));
  const float fm = (float)mean;
  out4[m * HW4 + q] = make_float4((x.x - fm) * istd, (x.y - fm) * istd,
                                  (x.z - fm) * istd, (x.w - fm) * istd);
}

extern "C" void kernel_launch(void* const* d_in, const int* in_sizes, int n_in,
                              void* d_out, int out_size, void* d_ws, size_t ws_size,
                              hipStream_t stream) {
  const float4* A4 = (const float4*)d_in[0];  // masks_a  [N,H,W]
  const float* sa  = (const float*)d_in[1];   // sims     [N]
  const float4* B4 = (const float4*)d_in[2];  // masks_b  [N,H,W]
  const float* st  = (const float*)d_in[3];   // sims_texture [N]
  const float* sc  = (const float*)d_in[4];   // sims_color   [N]
  const float* ss  = (const float*)d_in[5];   // sims_shape   [N]
  float4* out4 = (float4*)d_out;              // [4,H,W] fp32

  // workspace: [0,64)        : 8 doubles (stats)
  //            [64, 64+6*HW*4): partial sums
  double* stats = (double*)d_ws;
  float* part = (float*)((char*)d_ws + 64);

  hipMemsetAsync(d_ws, 0, 64 + (size_t)6 * HW * sizeof(float), stream);

  dim3 g1(HW4 / 256, NCHUNK);
  relax_partial<<<g1, 256, 0, stream>>>(A4, (const float4*)B4, sa, st, sc, ss, part);
  relax_stats<<<dim3(HW4 / 256), 256, 0, stream>>>((const float4*)part, stats);
  relax_norm<<<dim3(HW4 / 256, 4), 256, 0, stream>>>((const float4*)part, stats, out4);
}

// Round 3
// 149.249 us; speedup vs baseline: 1.1243x; 1.1037x over previous
//
#include <hip/hip_runtime.h>
#include <math.h>

#define HW (224 * 224)          // 50176 pixels
#define HW4 (HW / 4)            // 12544 float4 pixel-groups (= 49*256)
#define NSAMP 1024
#define NCHUNK 32
#define CHUNK (NSAMP / NCHUNK)  // 32 samples per chunk
#define EPSW 1e-10f
#define PXBLK (HW4 / 256)       // 49

__device__ __forceinline__ void fma4(float4& acc, const float4 m, const float s) {
  acc.x = fmaf(m.x, s, acc.x);
  acc.y = fmaf(m.y, s, acc.y);
  acc.z = fmaf(m.z, s, acc.z);
  acc.w = fmaf(m.w, s, acc.w);
}
__device__ __forceinline__ void add4(float4& acc, const float4 m) {
  acc.x += m.x; acc.y += m.y; acc.z += m.z; acc.w += m.w;
}
__device__ __forceinline__ void accstat(const float4 x, double& s, double& s2) {
  s  += (double)x.x + (double)x.y + (double)x.z + (double)x.w;
  s2 += (double)x.x * x.x + (double)x.y * x.y + (double)x.z * x.z + (double)x.w * x.w;
}

// ---- shared load+accumulate engine over one chunk (8 loads kept in flight) ----
struct Acc6 { float4 Wa, Sa, Wb, St, Sc, Ss; };

__device__ __forceinline__ Acc6 chunk_accumulate(
    const float4* __restrict__ ap, const float4* __restrict__ bp,
    const float4* __restrict__ s4) {
  Acc6 r;
  r.Wa = r.Sa = r.Wb = r.St = r.Sc = r.Ss = make_float4(0, 0, 0, 0);

  float4 abuf[2][4], bbuf[2][4];
#pragma unroll
  for (int k = 0; k < 4; ++k) {
    abuf[0][k] = ap[(size_t)k * HW4];
    bbuf[0][k] = bp[(size_t)k * HW4];
  }
#pragma unroll
  for (int g = 0; g < CHUNK / 4; ++g) {
    const int cur = g & 1;           // static after full unroll
    if (g + 1 < CHUNK / 4) {
#pragma unroll
      for (int k = 0; k < 4; ++k) {
        abuf[cur ^ 1][k] = ap[(size_t)((g + 1) * 4 + k) * HW4];
        bbuf[cur ^ 1][k] = bp[(size_t)((g + 1) * 4 + k) * HW4];
      }
    }
#pragma unroll
    for (int k = 0; k < 4; ++k) {
      const float4 ma = abuf[cur][k], mb = bbuf[cur][k];
      const float4 sv = s4[g * 4 + k];
      add4(r.Wa, ma);
      fma4(r.Sa, ma, sv.x);
      add4(r.Wb, mb);
      fma4(r.St, mb, sv.y);
      fma4(r.Sc, mb, sv.z);
      fma4(r.Ss, mb, sv.w);
    }
  }
  return r;
}

// -------- Kernel 1 (main path): per-chunk partials, clean vector stores --------
// part layout: part[chunk][6][HW4] float4
__global__ __launch_bounds__(256) void relax_partial(
    const float4* __restrict__ A4, const float4* __restrict__ B4,
    const float* __restrict__ sa, const float* __restrict__ st,
    const float* __restrict__ sc, const float* __restrict__ ss,
    float4* __restrict__ part) {
  __shared__ float4 s4[CHUNK];
  const int tid = threadIdx.x;
  const int c = blockIdx.y;
  const int i0 = c * CHUNK;
  if (tid < CHUNK)
    s4[tid] = make_float4(sa[i0 + tid], st[i0 + tid], sc[i0 + tid], ss[i0 + tid]);
  __syncthreads();

  const int q = blockIdx.x * 256 + tid;
  const Acc6 r = chunk_accumulate(A4 + (size_t)i0 * HW4 + q,
                                  B4 + (size_t)i0 * HW4 + q, s4);

  float4* w = part + (size_t)c * 6 * HW4 + q;
  w[0 * HW4] = r.Wa; w[1 * HW4] = r.Sa; w[2 * HW4] = r.Wb;
  w[3 * HW4] = r.St; w[4 * HW4] = r.Sc; w[5 * HW4] = r.Ss;
}

// -------- Kernel 1b (fallback if ws too small): atomic accumulate --------
__global__ __launch_bounds__(256) void relax_partial_atomic(
    const float4* __restrict__ A4, const float4* __restrict__ B4,
    const float* __restrict__ sa, const float* __restrict__ st,
    const float* __restrict__ sc, const float* __restrict__ ss,
    float* __restrict__ part6) {  // [6][HW]
  __shared__ float4 s4[CHUNK];
  const int tid = threadIdx.x;
  const int i0 = blockIdx.y * CHUNK;
  if (tid < CHUNK)
    s4[tid] = make_float4(sa[i0 + tid], st[i0 + tid], sc[i0 + tid], ss[i0 + tid]);
  __syncthreads();

  const int q = blockIdx.x * 256 + tid;
  const Acc6 r = chunk_accumulate(A4 + (size_t)i0 * HW4 + q,
                                  B4 + (size_t)i0 * HW4 + q, s4);
  const int p = 4 * q;
  const float* v;
  float* w;
  w = &part6[0 * HW + p]; v = &r.Wa.x;
  atomicAdd(w, v[0]); atomicAdd(w + 1, v[1]); atomicAdd(w + 2, v[2]); atomicAdd(w + 3, v[3]);
  w = &part6[1 * HW + p]; v = &r.Sa.x;
  atomicAdd(w, v[0]); atomicAdd(w + 1, v[1]); atomicAdd(w + 2, v[2]); atomicAdd(w + 3, v[3]);
  w = &part6[2 * HW + p]; v = &r.Wb.x;
  atomicAdd(w, v[0]); atomicAdd(w + 1, v[1]); atomicAdd(w + 2, v[2]); atomicAdd(w + 3, v[3]);
  w = &part6[3 * HW + p]; v = &r.St.x;
  atomicAdd(w, v[0]); atomicAdd(w + 1, v[1]); atomicAdd(w + 2, v[2]); atomicAdd(w + 3, v[3]);
  w = &part6[4 * HW + p]; v = &r.Sc.x;
  atomicAdd(w, v[0]); atomicAdd(w + 1, v[1]); atomicAdd(w + 2, v[2]); atomicAdd(w + 3, v[3]);
  w = &part6[5 * HW + p]; v = &r.Ss.x;
  atomicAdd(w, v[0]); atomicAdd(w + 1, v[1]); atomicAdd(w + 2, v[2]); atomicAdd(w + 3, v[3]);
}

// ---- shared: compute x-maps from 6 sums, write xmap, accumulate stats ----
__device__ __forceinline__ void finish_pixel(
    const float4 Wa, const float4 Sa, const float4 Wb,
    const float4 St, const float4 Sc, const float4 Ss,
    int q, float4* __restrict__ xmap, double* __restrict__ stats) {
  const float4 x0 = make_float4(Sa.x / (EPSW + Wa.x), Sa.y / (EPSW + Wa.y),
                                Sa.z / (EPSW + Wa.z), Sa.w / (EPSW + Wa.w));
  const float4 inv = make_float4(1.f / (EPSW + Wb.x), 1.f / (EPSW + Wb.y),
                                 1.f / (EPSW + Wb.z), 1.f / (EPSW + Wb.w));
  const float4 x1 = make_float4(St.x * inv.x, St.y * inv.y, St.z * inv.z, St.w * inv.w);
  const float4 x2 = make_float4(Sc.x * inv.x, Sc.y * inv.y, Sc.z * inv.z, Sc.w * inv.w);
  const float4 x3 = make_float4(Ss.x * inv.x, Ss.y * inv.y, Ss.z * inv.z, Ss.w * inv.w);

  xmap[0 * HW4 + q] = x0;
  xmap[1 * HW4 + q] = x1;
  xmap[2 * HW4 + q] = x2;
  xmap[3 * HW4 + q] = x3;

  double v[8] = {0, 0, 0, 0, 0, 0, 0, 0};
  accstat(x0, v[0], v[1]);
  accstat(x1, v[2], v[3]);
  accstat(x2, v[4], v[5]);
  accstat(x3, v[6], v[7]);
#pragma unroll
  for (int k = 0; k < 8; ++k)
#pragma unroll
    for (int off = 32; off; off >>= 1)
      v[k] += __shfl_down(v[k], off);
  if ((threadIdx.x & 63) == 0) {
#pragma unroll
    for (int k = 0; k < 8; ++k) atomicAdd(&stats[k], v[k]);
  }
}

// -------- Kernel 2 (main): reduce 32 chunks (L2/L3-hot) + stats --------
__global__ __launch_bounds__(256) void relax_reduce(
    const float4* __restrict__ part, float4* __restrict__ xmap,
    double* __restrict__ stats) {
  const int q = blockIdx.x * 256 + threadIdx.x;
  float4 a0 = {0,0,0,0}, a1 = {0,0,0,0}, a2 = {0,0,0,0};
  float4 a3 = {0,0,0,0}, a4 = {0,0,0,0}, a5 = {0,0,0,0};
#pragma unroll 4
  for (int c = 0; c < NCHUNK; ++c) {
    const float4* w = part + (size_t)c * 6 * HW4 + q;
    const float4 t0 = w[0 * HW4], t1 = w[1 * HW4], t2 = w[2 * HW4];
    const float4 t3 = w[3 * HW4], t4 = w[4 * HW4], t5 = w[5 * HW4];
    add4(a0, t0); add4(a1, t1); add4(a2, t2);
    add4(a3, t3); add4(a4, t4); add4(a5, t5);
  }
  finish_pixel(a0, a1, a2, a3, a4, a5, q, xmap, stats);
}

// -------- Kernel 2b (fallback): part6 -> xmap + stats --------
__global__ __launch_bounds__(256) void relax_reduce_atomicpath(
    const float4* __restrict__ part6, float4* __restrict__ xmap,
    double* __restrict__ stats) {
  const int q = blockIdx.x * 256 + threadIdx.x;
  finish_pixel(part6[0 * HW4 + q], part6[1 * HW4 + q], part6[2 * HW4 + q],
               part6[3 * HW4 + q], part6[4 * HW4 + q], part6[5 * HW4 + q],
               q, xmap, stats);
}

// -------- Kernel 3: normalize --------
__global__ __launch_bounds__(256) void relax_norm(
    const float4* __restrict__ xmap, const double* __restrict__ stats,
    float4* __restrict__ out4) {
  const int q = blockIdx.x * 256 + threadIdx.x;
  const int m = blockIdx.y;
  const float4 x = xmap[m * HW4 + q];
  const double sum = stats[2 * m], sumsq = stats[2 * m + 1];
  const double mean = sum / (double)HW;
  const double var = (sumsq - sum * sum / (double)HW) / (double)(HW - 1);
  const float istd = (float)(1.0 / sqrt(var));
  const float fm = (float)mean;
  out4[m * HW4 + q] = make_float4((x.x - fm) * istd, (x.y - fm) * istd,
                                  (x.z - fm) * istd, (x.w - fm) * istd);
}

extern "C" void kernel_launch(void* const* d_in, const int* in_sizes, int n_in,
                              void* d_out, int out_size, void* d_ws, size_t ws_size,
                              hipStream_t stream) {
  const float4* A4 = (const float4*)d_in[0];  // masks_a [N,H,W]
  const float* sa  = (const float*)d_in[1];   // sims [N]
  const float4* B4 = (const float4*)d_in[2];  // masks_b [N,H,W]
  const float* st  = (const float*)d_in[3];
  const float* sc  = (const float*)d_in[4];
  const float* ss  = (const float*)d_in[5];
  float4* out4 = (float4*)d_out;              // [4,H,W]

  // ws layout: [0,64) stats (8 doubles) | [64, 64+4*HW*4) xmap | rest: partials
  double* stats = (double*)d_ws;
  float4* xmap = (float4*)((char*)d_ws + 64);
  char* rest = (char*)d_ws + 64 + (size_t)4 * HW * sizeof(float);
  const size_t need_main =
      64 + (size_t)4 * HW * sizeof(float) + (size_t)NCHUNK * 6 * HW * sizeof(float);

  hipMemsetAsync(d_ws, 0, 64, stream);  // stats only

  if (ws_size >= need_main) {
    float4* part = (float4*)rest;  // [NCHUNK][6][HW4]
    relax_partial<<<dim3(PXBLK, NCHUNK), 256, 0, stream>>>(A4, B4, sa, st, sc, ss, part);
    relax_reduce<<<dim3(PXBLK), 256, 0, stream>>>(part, xmap, stats);
  } else {
    float* part6 = (float*)rest;   // [6][HW]
    hipMemsetAsync(part6, 0, (size_t)6 * HW * sizeof(float), stream);
    relax_partial_atomic<<<dim3(PXBLK, NCHUNK), 256, 0, stream>>>(A4, B4, sa, st, sc, ss, part6);
    relax_reduce_atomicpath<<<dim3(PXBLK), 256, 0, stream>>>((const float4*)part6, xmap, stats);
  }
  relax_norm<<<dim3(PXBLK, 4), 256, 0, stream>>>(xmap, stats, out4);
}

// Round 4
// 142.596 us; speedup vs baseline: 1.1768x; 1.0467x over previous
//
#include <hip/hip_runtime.h>
#include <math.h>

#define HW (224 * 224)          // 50176 pixels
#define HW4 (HW / 4)            // 12544 float4 pixel-groups (= 49*256)
#define NSAMP 1024
#define NCHUNK 16
#define CHUNK (NSAMP / NCHUNK)  // 64 samples per chunk
#define NGRP (CHUNK / 4)        // 16 groups of 4 samples
#define EPSW 1e-10f
#define PXBLK (HW4 / 256)       // 49

typedef float v4f __attribute__((ext_vector_type(4)));

// Non-temporal float4 load: nt-flagged global_load_dwordx4, bypasses cache
// allocation for read-once streaming data (theory: frees the ~3 TB/s L3
// streaming wall; values identical either way).
__device__ __forceinline__ float4 ntload4(const float4* p) {
  v4f v = __builtin_nontemporal_load((const v4f*)p);
  return make_float4(v[0], v[1], v[2], v[3]);
}

__device__ __forceinline__ void fma4(float4& acc, const float4 m, const float s) {
  acc.x = fmaf(m.x, s, acc.x);
  acc.y = fmaf(m.y, s, acc.y);
  acc.z = fmaf(m.z, s, acc.z);
  acc.w = fmaf(m.w, s, acc.w);
}
__device__ __forceinline__ void add4(float4& acc, const float4 m) {
  acc.x += m.x; acc.y += m.y; acc.z += m.z; acc.w += m.w;
}
__device__ __forceinline__ void accstat(const float4 x, double& s, double& s2) {
  s  += (double)x.x + (double)x.y + (double)x.z + (double)x.w;
  s2 += (double)x.x * x.x + (double)x.y * x.y + (double)x.z * x.z + (double)x.w * x.w;
}

// ---- load+accumulate over one chunk, double-buffered (8 loads in flight) ----
struct Acc6 { float4 Wa, Sa, Wb, St, Sc, Ss; };

__device__ __forceinline__ Acc6 chunk_accumulate(
    const float4* __restrict__ ap, const float4* __restrict__ bp,
    const float4* __restrict__ s4) {
  Acc6 r;
  r.Wa = r.Sa = r.Wb = r.St = r.Sc = r.Ss = make_float4(0, 0, 0, 0);

  float4 abuf[2][4], bbuf[2][4];
#pragma unroll
  for (int k = 0; k < 4; ++k) {
    abuf[0][k] = ntload4(ap + (size_t)k * HW4);
    bbuf[0][k] = ntload4(bp + (size_t)k * HW4);
  }
#pragma unroll
  for (int g = 0; g < NGRP; ++g) {
    const int cur = g & 1;  // static after full unroll
    if (g + 1 < NGRP) {
#pragma unroll
      for (int k = 0; k < 4; ++k) {
        abuf[cur ^ 1][k] = ntload4(ap + (size_t)((g + 1) * 4 + k) * HW4);
        bbuf[cur ^ 1][k] = ntload4(bp + (size_t)((g + 1) * 4 + k) * HW4);
      }
    }
#pragma unroll
    for (int k = 0; k < 4; ++k) {
      const float4 ma = abuf[cur][k], mb = bbuf[cur][k];
      const float4 sv = s4[g * 4 + k];
      add4(r.Wa, ma);
      fma4(r.Sa, ma, sv.x);
      add4(r.Wb, mb);
      fma4(r.St, mb, sv.y);
      fma4(r.Sc, mb, sv.z);
      fma4(r.Ss, mb, sv.w);
    }
  }
  return r;
}

// -------- Kernel 1: per-chunk partials, clean vector stores --------
// part layout: part[chunk][6][HW4] float4
__global__ __launch_bounds__(256) void relax_partial(
    const float4* __restrict__ A4, const float4* __restrict__ B4,
    const float* __restrict__ sa, const float* __restrict__ st,
    const float* __restrict__ sc, const float* __restrict__ ss,
    float4* __restrict__ part) {
  __shared__ float4 s4[CHUNK];
  const int tid = threadIdx.x;
  const int c = blockIdx.y;
  const int i0 = c * CHUNK;
  if (tid < CHUNK)
    s4[tid] = make_float4(sa[i0 + tid], st[i0 + tid], sc[i0 + tid], ss[i0 + tid]);
  __syncthreads();

  const int q = blockIdx.x * 256 + tid;
  const Acc6 r = chunk_accumulate(A4 + (size_t)i0 * HW4 + q,
                                  B4 + (size_t)i0 * HW4 + q, s4);

  float4* w = part + (size_t)c * 6 * HW4 + q;
  w[0 * HW4] = r.Wa; w[1 * HW4] = r.Sa; w[2 * HW4] = r.Wb;
  w[3 * HW4] = r.St; w[4 * HW4] = r.Sc; w[5 * HW4] = r.Ss;
}

// -------- Kernel 1b (fallback if ws too small): atomic accumulate --------
__global__ __launch_bounds__(256) void relax_partial_atomic(
    const float4* __restrict__ A4, const float4* __restrict__ B4,
    const float* __restrict__ sa, const float* __restrict__ st,
    const float* __restrict__ sc, const float* __restrict__ ss,
    float* __restrict__ part6) {  // [6][HW]
  __shared__ float4 s4[CHUNK];
  const int tid = threadIdx.x;
  const int i0 = blockIdx.y * CHUNK;
  if (tid < CHUNK)
    s4[tid] = make_float4(sa[i0 + tid], st[i0 + tid], sc[i0 + tid], ss[i0 + tid]);
  __syncthreads();

  const int q = blockIdx.x * 256 + tid;
  const Acc6 r = chunk_accumulate(A4 + (size_t)i0 * HW4 + q,
                                  B4 + (size_t)i0 * HW4 + q, s4);
  const int p = 4 * q;
  const float* v;
  float* w;
  w = &part6[0 * HW + p]; v = &r.Wa.x;
  atomicAdd(w, v[0]); atomicAdd(w + 1, v[1]); atomicAdd(w + 2, v[2]); atomicAdd(w + 3, v[3]);
  w = &part6[1 * HW + p]; v = &r.Sa.x;
  atomicAdd(w, v[0]); atomicAdd(w + 1, v[1]); atomicAdd(w + 2, v[2]); atomicAdd(w + 3, v[3]);
  w = &part6[2 * HW + p]; v = &r.Wb.x;
  atomicAdd(w, v[0]); atomicAdd(w + 1, v[1]); atomicAdd(w + 2, v[2]); atomicAdd(w + 3, v[3]);
  w = &part6[3 * HW + p]; v = &r.St.x;
  atomicAdd(w, v[0]); atomicAdd(w + 1, v[1]); atomicAdd(w + 2, v[2]); atomicAdd(w + 3, v[3]);
  w = &part6[4 * HW + p]; v = &r.Sc.x;
  atomicAdd(w, v[0]); atomicAdd(w + 1, v[1]); atomicAdd(w + 2, v[2]); atomicAdd(w + 3, v[3]);
  w = &part6[5 * HW + p]; v = &r.Ss.x;
  atomicAdd(w, v[0]); atomicAdd(w + 1, v[1]); atomicAdd(w + 2, v[2]); atomicAdd(w + 3, v[3]);
}

// ---- shared: x-maps from 6 sums, write xmap, accumulate stats ----
__device__ __forceinline__ void finish_pixel(
    const float4 Wa, const float4 Sa, const float4 Wb,
    const float4 St, const float4 Sc, const float4 Ss,
    int q, float4* __restrict__ xmap, double* __restrict__ stats) {
  const float4 x0 = make_float4(Sa.x / (EPSW + Wa.x), Sa.y / (EPSW + Wa.y),
                                Sa.z / (EPSW + Wa.z), Sa.w / (EPSW + Wa.w));
  const float4 inv = make_float4(1.f / (EPSW + Wb.x), 1.f / (EPSW + Wb.y),
                                 1.f / (EPSW + Wb.z), 1.f / (EPSW + Wb.w));
  const float4 x1 = make_float4(St.x * inv.x, St.y * inv.y, St.z * inv.z, St.w * inv.w);
  const float4 x2 = make_float4(Sc.x * inv.x, Sc.y * inv.y, Sc.z * inv.z, Sc.w * inv.w);
  const float4 x3 = make_float4(Ss.x * inv.x, Ss.y * inv.y, Ss.z * inv.z, Ss.w * inv.w);

  xmap[0 * HW4 + q] = x0;
  xmap[1 * HW4 + q] = x1;
  xmap[2 * HW4 + q] = x2;
  xmap[3 * HW4 + q] = x3;

  double v[8] = {0, 0, 0, 0, 0, 0, 0, 0};
  accstat(x0, v[0], v[1]);
  accstat(x1, v[2], v[3]);
  accstat(x2, v[4], v[5]);
  accstat(x3, v[6], v[7]);
#pragma unroll
  for (int k = 0; k < 8; ++k)
#pragma unroll
    for (int off = 32; off; off >>= 1)
      v[k] += __shfl_down(v[k], off);
  if ((threadIdx.x & 63) == 0) {
#pragma unroll
    for (int k = 0; k < 8; ++k) atomicAdd(&stats[k], v[k]);
  }
}

// -------- Kernel 2: reduce NCHUNK chunks + stats --------
__global__ __launch_bounds__(256) void relax_reduce(
    const float4* __restrict__ part, float4* __restrict__ xmap,
    double* __restrict__ stats) {
  const int q = blockIdx.x * 256 + threadIdx.x;
  float4 a0 = {0,0,0,0}, a1 = {0,0,0,0}, a2 = {0,0,0,0};
  float4 a3 = {0,0,0,0}, a4 = {0,0,0,0}, a5 = {0,0,0,0};
#pragma unroll 4
  for (int c = 0; c < NCHUNK; ++c) {
    const float4* w = part + (size_t)c * 6 * HW4 + q;
    const float4 t0 = w[0 * HW4], t1 = w[1 * HW4], t2 = w[2 * HW4];
    const float4 t3 = w[3 * HW4], t4 = w[4 * HW4], t5 = w[5 * HW4];
    add4(a0, t0); add4(a1, t1); add4(a2, t2);
    add4(a3, t3); add4(a4, t4); add4(a5, t5);
  }
  finish_pixel(a0, a1, a2, a3, a4, a5, q, xmap, stats);
}

// -------- Kernel 2b (fallback): part6 -> xmap + stats --------
__global__ __launch_bounds__(256) void relax_reduce_atomicpath(
    const float4* __restrict__ part6, float4* __restrict__ xmap,
    double* __restrict__ stats) {
  const int q = blockIdx.x * 256 + threadIdx.x;
  finish_pixel(part6[0 * HW4 + q], part6[1 * HW4 + q], part6[2 * HW4 + q],
               part6[3 * HW4 + q], part6[4 * HW4 + q], part6[5 * HW4 + q],
               q, xmap, stats);
}

// -------- Kernel 3: normalize --------
__global__ __launch_bounds__(256) void relax_norm(
    const float4* __restrict__ xmap, const double* __restrict__ stats,
    float4* __restrict__ out4) {
  const int q = blockIdx.x * 256 + threadIdx.x;
  const int m = blockIdx.y;
  const float4 x = xmap[m * HW4 + q];
  const double sum = stats[2 * m], sumsq = stats[2 * m + 1];
  const double mean = sum / (double)HW;
  const double var = (sumsq - sum * sum / (double)HW) / (double)(HW - 1);
  const float istd = (float)(1.0 / sqrt(var));
  const float fm = (float)mean;
  out4[m * HW4 + q] = make_float4((x.x - fm) * istd, (x.y - fm) * istd,
                                  (x.z - fm) * istd, (x.w - fm) * istd);
}

extern "C" void kernel_launch(void* const* d_in, const int* in_sizes, int n_in,
                              void* d_out, int out_size, void* d_ws, size_t ws_size,
                              hipStream_t stream) {
  const float4* A4 = (const float4*)d_in[0];  // masks_a [N,H,W]
  const float* sa  = (const float*)d_in[1];   // sims [N]
  const float4* B4 = (const float4*)d_in[2];  // masks_b [N,H,W]
  const float* st  = (const float*)d_in[3];
  const float* sc  = (const float*)d_in[4];
  const float* ss  = (const float*)d_in[5];
  float4* out4 = (float4*)d_out;              // [4,H,W]

  // ws layout: [0,64) stats (8 doubles) | [64, 64+4*HW*4) xmap | rest: partials
  double* stats = (double*)d_ws;
  float4* xmap = (float4*)((char*)d_ws + 64);
  char* rest = (char*)d_ws + 64 + (size_t)4 * HW * sizeof(float);
  const size_t need_main =
      64 + (size_t)4 * HW * sizeof(float) + (size_t)NCHUNK * 6 * HW * sizeof(float);

  hipMemsetAsync(d_ws, 0, 64, stream);  // stats only

  if (ws_size >= need_main) {
    float4* part = (float4*)rest;  // [NCHUNK][6][HW4]
    relax_partial<<<dim3(PXBLK, NCHUNK), 256, 0, stream>>>(A4, B4, sa, st, sc, ss, part);
    relax_reduce<<<dim3(PXBLK), 256, 0, stream>>>(part, xmap, stats);
  } else {
    float* part6 = (float*)rest;   // [6][HW]
    hipMemsetAsync(part6, 0, (size_t)6 * HW * sizeof(float), stream);
    relax_partial_atomic<<<dim3(PXBLK, NCHUNK), 256, 0, stream>>>(A4, B4, sa, st, sc, ss, part6);
    relax_reduce_atomicpath<<<dim3(PXBLK), 256, 0, stream>>>((const float4*)part6, xmap, stats);
  }
  relax_norm<<<dim3(PXBLK, 4), 256, 0, stream>>>(xmap, stats, out4);
}